// Round 4
// baseline (4833.714 us; speedup 1.0000x reference)
//
#include <hip/hip_runtime.h>
#include <stdint.h>

#define T_SEQ 512
#define BATCH 256
#define HID   128
#define G4    512   // 4*H
#define XD    257
#define ZD    16

typedef short  bf16x8 __attribute__((ext_vector_type(8)));
typedef float  f32x4  __attribute__((ext_vector_type(4)));

#define MFMA(a,b,c) __builtin_amdgcn_mfma_f32_16x16x32_bf16((a),(b),(c),0,0,0)

// packed B-fragment segment offsets (uint4 units)
#define OHH_GX 0        // Whh_gx: 32 tiles x KT4, perm
#define OHH_GZ 8192     // Whh_gz + Wih_gz at kt4: 32 x KT5, perm
#define OHH_H  18432    // Whh_h  + Wih_h  at kt4: 32 x KT5, perm
#define OW0    28672    // W0: 8 x KT8, noperm (K=256)
#define OWM    32768    // Wm: 1 x KT4, noperm
#define OWV    33024    // Wv: 1 x KT4, noperm
#define OPX    33280    // Wih_gx as B (rows=j 512, K=257 pad 288): 32 x KT9
#define OPY    51712    // Wy (rows=d<257 pad 272, K=128): 17 x KT4
#define NPACK  56064

// ---------- helpers ----------
__device__ __forceinline__ float bf2f(uint16_t u) {
  union { uint32_t i; float f; } v; v.i = ((uint32_t)u) << 16; return v.f;
}
__device__ __forceinline__ uint16_t f2bf(float f) {
  union { float f; uint32_t i; } v; v.f = f;
  uint32_t r = v.i + 0x7fffu + ((v.i >> 16) & 1u);
  return (uint16_t)(r >> 16);
}
__device__ __forceinline__ float tanhfast(float x) { return 2.0f / (1.0f + __expf(-2.0f * x)) - 1.0f; }
__device__ __forceinline__ float gate_act(float pre, bool isg) {
  float s = isg ? (-2.0f * pre) : (-pre);
  float r = 1.0f / (1.0f + __expf(s));
  return isg ? (2.0f * r - 1.0f) : r;
}

// ---------- kernel 1: pack all weights into MFMA B-fragments (bf16) ----------
// frag layout: seg[(tile*KT + kt)*64 + lane] = 8 bf16 (one uint4)
// element: n = tile*16 + (lane&15) -> row r (perm or natural), k = kt*32 + (lane>>4)*8 + j
// perm (512-row LSTM weights): r = (tile&3)*128 + (tile>>2)*16 + (lane&15)
// KT5 segments: kt==4 holds the K=16 Wih weights (zero-padded to 32)
__global__ __launch_bounds__(256) void k_pack(
    const float* __restrict__ Whh_gx, const float* __restrict__ Whh_gz,
    const float* __restrict__ Whh_h,  const float* __restrict__ Wih_gz,
    const float* __restrict__ Wih_h,  const float* __restrict__ W0,
    const float* __restrict__ Wm,     const float* __restrict__ Wv,
    const float* __restrict__ Wih_gx, const float* __restrict__ Wy,
    uint4* __restrict__ out) {
  int idx = blockIdx.x * 256 + threadIdx.x;
  if (idx >= NPACK) return;
  const float* W; const float* Wx = nullptr;
  int Kreal, KT, base, rowMax = 1 << 30; bool perm;
  if      (idx < OHH_GZ) { W = Whh_gx; Kreal = 128; KT = 4; perm = true;  base = OHH_GX; }
  else if (idx < OHH_H ) { W = Whh_gz; Wx = Wih_gz; Kreal = 128; KT = 5; perm = true; base = OHH_GZ; }
  else if (idx < OW0   ) { W = Whh_h;  Wx = Wih_h;  Kreal = 128; KT = 5; perm = true; base = OHH_H; }
  else if (idx < OWM   ) { W = W0;     Kreal = 256; KT = 8; perm = false; base = OW0; }
  else if (idx < OWV   ) { W = Wm;     Kreal = 128; KT = 4; perm = false; base = OWM; }
  else if (idx < OPX   ) { W = Wv;     Kreal = 128; KT = 4; perm = false; base = OWV; }
  else if (idx < OPY   ) { W = Wih_gx; Kreal = 257; KT = 9; perm = false; base = OPX; }
  else                   { W = Wy;     Kreal = 128; KT = 4; perm = false; base = OPY; rowMax = XD; }
  int li = idx - base;
  int lane = li & 63, rest = li >> 6;
  int kt = rest % KT, tile = rest / KT;
  int n15 = lane & 15, quad = lane >> 4;
  int r = perm ? ((tile & 3) * 128 + (tile >> 2) * 16 + n15) : (tile * 16 + n15);
  bool rok = (r < rowMax);
  uint16_t v[8];
  if (Wx != nullptr && kt == 4) {
    // folded Wih slot: K=16 data in a K=32 tile
#pragma unroll
    for (int j = 0; j < 8; ++j) {
      int k2 = quad * 8 + j;
      float f = (k2 < ZD && rok) ? Wx[(size_t)r * ZD + k2] : 0.0f;
      v[j] = f2bf(f);
    }
  } else {
    int k0 = kt * 32 + quad * 8;
#pragma unroll
    for (int j = 0; j < 8; ++j) {
      float f = (k0 + j < Kreal && rok) ? W[(size_t)r * Kreal + k0 + j] : 0.0f;
      v[j] = f2bf(f);
    }
  }
  uint4 o4;
  o4.x = (uint32_t)v[0] | ((uint32_t)v[1] << 16);
  o4.y = (uint32_t)v[2] | ((uint32_t)v[3] << 16);
  o4.z = (uint32_t)v[4] | ((uint32_t)v[5] << 16);
  o4.w = (uint32_t)v[6] | ((uint32_t)v[7] << 16);
  out[idx] = o4;
}

// ---------- kernel 2: px = bias + x @ Wih_gx^T via MFMA ----------
// block: (t-tile 4) x (b-tile 16) = 64 M-rows; 256 thr (4 waves, wave w -> gate cols w*128..+127)
__global__ __launch_bounds__(256) void k_proj2(
    const float* __restrict__ x, const uint4* __restrict__ pk,
    const float* __restrict__ bih, const float* __restrict__ bhh,
    uint16_t* __restrict__ px) {
  __shared__ uint16_t xs[4][16 * 296];   // [tt][b][296], d pad 257->296 (zero)
  int tid = threadIdx.x;
  int t0 = blockIdx.x * 4, b0 = blockIdx.y * 16;
  for (int base = 0; base < 4 * 16 * 296; base += 256) {
    int idx = base + tid;                      // idx = (d*16 + bb)*4 + tt
    int tt = idx & 3, bb = (idx >> 2) & 15, d = idx >> 6;
    float v = (d < XD) ? x[((size_t)(b0 + bb) * XD + d) * T_SEQ + t0 + tt] : 0.0f;
    xs[tt][bb * 296 + d] = f2bf(v);
  }
  __syncthreads();
  int lane = tid & 63, w = tid >> 6;
  int n15 = lane & 15, quad = lane >> 4;
  const bf16x8* pkb = (const bf16x8*)pk;
  float bias[8];
#pragma unroll
  for (int ntl = 0; ntl < 8; ++ntl) {
    int j = (w * 8 + ntl) * 16 + n15;
    bias[ntl] = bih[j] + bhh[j];
  }
  for (int mt = 0; mt < 4; ++mt) {
    bf16x8 af[9];
#pragma unroll
    for (int kt = 0; kt < 9; ++kt)
      af[kt] = *(const bf16x8*)&xs[mt][n15 * 296 + kt * 32 + quad * 8];
#pragma unroll
    for (int ntl = 0; ntl < 8; ++ntl) {
      int nt = w * 8 + ntl;
      f32x4 acc = {bias[ntl], bias[ntl], bias[ntl], bias[ntl]};
#pragma unroll
      for (int kt = 0; kt < 9; ++kt)
        acc = MFMA(af[kt], pkb[OPX + (nt * 9 + kt) * 64 + lane], acc);
#pragma unroll
      for (int reg = 0; reg < 4; ++reg)
        px[((size_t)(t0 + mt) * BATCH + b0 + quad * 4 + reg) * G4 + nt * 16 + n15] = f2bf(acc[reg]);
    }
  }
}

// ---------- kernel 3: backward LSTM g_x — MFMA, LDS-chunked gx output ----------
__global__ __launch_bounds__(512, 2) void k_lstm_gx(
    const uint16_t* __restrict__ px, const uint4* __restrict__ pk,
    uint16_t* __restrict__ gx) {
  __shared__ uint16_t hl[2][16 * 136];
  __shared__ uint16_t gxc[8][16 * HID];   // 8-step output chunk (32 KB)
  int tid = threadIdx.x, b0 = blockIdx.x * 16;
  int lane = tid & 63, w = tid >> 6;
  int n15 = lane & 15, quad = lane >> 4;
  const bf16x8* pkb = (const bf16x8*)pk;
  bf16x8 whh[4][4];
#pragma unroll
  for (int ct = 0; ct < 4; ++ct)
#pragma unroll
    for (int kt = 0; kt < 4; ++kt)
      whh[ct][kt] = pkb[OHH_GX + ((4 * w + ct) * 4 + kt) * 64 + lane];
  for (int i = tid; i < 16 * 136; i += 512) hl[0][i] = 0;
  float c[4] = {0.f, 0.f, 0.f, 0.f};
  int cur = 0;
  uint16_t pxr[4][4];
#pragma unroll
  for (int ct = 0; ct < 4; ++ct) {
    int r = ct * 128 + w * 16 + n15;
#pragma unroll
    for (int reg = 0; reg < 4; ++reg)
      pxr[ct][reg] = px[((size_t)(T_SEQ - 1) * BATCH + b0 + quad * 4 + reg) * G4 + r];
  }
  __syncthreads();
  for (int t = T_SEQ - 1; t >= 0; --t) {
    bf16x8 a[4];
#pragma unroll
    for (int kt = 0; kt < 4; ++kt)
      a[kt] = *(const bf16x8*)&hl[cur][n15 * 136 + kt * 32 + quad * 8];
    int tn = t > 0 ? t - 1 : 0;
    uint16_t pxn[4][4];
#pragma unroll
    for (int ct = 0; ct < 4; ++ct) {
      int r = ct * 128 + w * 16 + n15;
#pragma unroll
      for (int reg = 0; reg < 4; ++reg)
        pxn[ct][reg] = px[((size_t)tn * BATCH + b0 + quad * 4 + reg) * G4 + r];
    }
    float act[4][4];
#pragma unroll
    for (int ct = 0; ct < 4; ++ct) {
      f32x4 acc = {bf2f(pxr[ct][0]), bf2f(pxr[ct][1]), bf2f(pxr[ct][2]), bf2f(pxr[ct][3])};
#pragma unroll
      for (int kt = 0; kt < 4; ++kt) acc = MFMA(a[kt], whh[ct][kt], acc);
#pragma unroll
      for (int reg = 0; reg < 4; ++reg) act[ct][reg] = gate_act(acc[reg], ct == 2);
    }
#pragma unroll
    for (int reg = 0; reg < 4; ++reg) {
      c[reg] = act[1][reg] * c[reg] + act[0][reg] * act[2][reg];
      float h = act[3][reg] * tanhfast(c[reg]);
      uint16_t hb = f2bf(h);
      int m = quad * 4 + reg;
      hl[cur ^ 1][m * 136 + w * 16 + n15] = hb;
      gxc[t & 7][m * HID + w * 16 + n15] = hb;
    }
#pragma unroll
    for (int ct = 0; ct < 4; ++ct)
#pragma unroll
      for (int reg = 0; reg < 4; ++reg) pxr[ct][reg] = pxn[ct][reg];
    cur ^= 1;
    __syncthreads();
    if ((t & 7) == 0) {   // flush t..t+7, fully coalesced
      const uint4* src = (const uint4*)gxc;
#pragma unroll
      for (int r = 0; r < 4; ++r) {
        int f = r * 512 + tid;               // 2048 uint4 total
        int tt = f >> 8, rem = f & 255;
        ((uint4*)(gx + ((size_t)(t + tt) * BATCH + b0) * HID))[rem] = src[f];
      }
      __syncthreads();
    }
  }
}

// decoder LSTM step for time tp (all 8 waves). Scoped macro to avoid code drift.
#define D_STEP(tp) do { \
  int dcur = (tp) & 1; \
  bf16x8 za_ = *(const bf16x8*)&zt[n15 * 40 + quad * 8]; \
  bf16x8 hdf[4]; \
  _Pragma("unroll") for (int kt = 0; kt < 4; ++kt) \
    hdf[kt] = *(const bf16x8*)&hdl[dcur][n15 * 136 + kt * 32 + quad * 8]; \
  float actd[4][4]; \
  _Pragma("unroll") for (int ct = 0; ct < 4; ++ct) { \
    f32x4 ga = {bzd[ct], bzd[ct], bzd[ct], bzd[ct]}; \
    _Pragma("unroll") for (int kt = 0; kt < 4; ++kt) ga = MFMA(hdf[kt], whd[ct][kt], ga); \
    ga = MFMA(za_, whd[ct][4], ga); \
    _Pragma("unroll") for (int reg = 0; reg < 4; ++reg) actd[ct][reg] = gate_act(ga[reg], ct == 2); \
  } \
  _Pragma("unroll") for (int reg = 0; reg < 4; ++reg) { \
    cd[reg] = actd[1][reg] * cd[reg] + actd[0][reg] * actd[2][reg]; \
    float hh = actd[3][reg] * tanhfast(cd[reg]); \
    uint16_t hb16 = f2bf(hh); \
    int m = quad * 4 + reg; \
    hdl[dcur ^ 1][m * 136 + w * 16 + n15] = hb16; \
    hdc[(tp) & 3][m * HID + w * 16 + n15] = hb16; \
  } \
} while (0)

// ---------- kernel 4: fused inference + decoder ----------
__global__ __launch_bounds__(512, 2) void k_infdec(
    const uint16_t* __restrict__ gx, const float* __restrict__ eps,
    const uint4* __restrict__ pk,
    const float* __restrict__ bih_gz, const float* __restrict__ bhh_gz,
    const float* __restrict__ b0, const float* __restrict__ bm,
    const float* __restrict__ bv,
    const float* __restrict__ bih_h, const float* __restrict__ bhh_h,
    uint16_t* __restrict__ hdec, float* __restrict__ out_mean,
    float* __restrict__ out_logvar, float* __restrict__ out_z) {
  __shared__ uint16_t gzl[2][16 * 136];
  __shared__ uint16_t hdl[2][16 * 136];
  __shared__ uint16_t gxl[2][16 * 136];
  __shared__ uint16_t hmlp[16 * 136];
  __shared__ uint16_t zt[16 * 40];
  __shared__ float means[16 * 17], lvs[16 * 17];
  __shared__ float mlzc[3][4 * 256];      // [arr][tt*256 + b*16+o], 4-step chunk
  __shared__ uint16_t hdc[4][16 * HID];   // 4-step hdec chunk (16 KB)
  __shared__ uint4 w0L[4096];             // W0 fragments (64 KB)
  int tid = threadIdx.x, b0i = blockIdx.x * 16;
  int lane = tid & 63, w = tid >> 6;
  int n15 = lane & 15, quad = lane >> 4;
  const bf16x8* pkb = (const bf16x8*)pk;
  bf16x8 whz[4][5], whd[4][5];
#pragma unroll
  for (int ct = 0; ct < 4; ++ct)
#pragma unroll
    for (int kt = 0; kt < 5; ++kt) {
      whz[ct][kt] = pkb[OHH_GZ + ((4 * w + ct) * 5 + kt) * 64 + lane];
      whd[ct][kt] = pkb[OHH_H + ((4 * w + ct) * 5 + kt) * 64 + lane];
    }
  bf16x8 wmf[4];
  if (w < 2) {
#pragma unroll
    for (int kt = 0; kt < 4; ++kt)
      wmf[kt] = pkb[(w == 0 ? OWM : OWV) + kt * 64 + lane];
  }
  float bzr[4], bzd[4];
#pragma unroll
  for (int ct = 0; ct < 4; ++ct) {
    int r = ct * 128 + w * 16 + n15;
    bzr[ct] = bih_gz[r] + bhh_gz[r];
    bzd[ct] = bih_h[r] + bhh_h[r];
  }
  float b0r = b0[w * 16 + n15];
  float bmv = (w == 0) ? bm[n15] : ((w == 1) ? bv[n15] : 0.0f);
  for (int i = tid; i < 16 * 136; i += 512) { gzl[0][i] = 0; hdl[0][i] = 0; }
  for (int i = tid; i < 16 * 40; i += 512) zt[i] = 0;
  for (int i = tid; i < 4096; i += 512) w0L[i] = pk[OW0 + i];
  uint4 vgx = {0, 0, 0, 0};
  float epr = 0.0f, epn = 0.0f;
  if (tid < 256) {
    vgx = ((const uint4*)(gx + (size_t)b0i * HID))[tid];
    epr = eps[(size_t)(b0i + (tid >> 4)) * ZD + (tid & 15)];
  }
  __syncthreads();
  if (tid < 256) *(uint4*)&gxl[0][(tid >> 4) * 136 + (tid & 15) * 8] = vgx;
  __syncthreads();
  float c[4] = {0.f, 0.f, 0.f, 0.f}, cd[4] = {0.f, 0.f, 0.f, 0.f};
  for (int t = 0; t < T_SEQ; ++t) {
    int cur = t & 1, tt = t & 3;
    // ---- phase 1: B(t) on all waves + D(t-1) on all waves (one step behind) ----
    int tn = (t < T_SEQ - 1) ? t + 1 : t;
    if (tid < 256) {
      vgx = ((const uint4*)(gx + (size_t)(tn * BATCH + b0i) * HID))[tid];
      epn = eps[((size_t)tn * BATCH + b0i + (tid >> 4)) * ZD + (tid & 15)];
    }
    {
      f32x4 hb = {b0r, b0r, b0r, b0r};
#pragma unroll
      for (int kt = 0; kt < 4; ++kt) {
        bf16x8 a = *(const bf16x8*)&gxl[cur][n15 * 136 + kt * 32 + quad * 8];
        hb = MFMA(a, ((const bf16x8*)w0L)[(w * 8 + kt) * 64 + lane], hb);
      }
#pragma unroll
      for (int kt = 0; kt < 4; ++kt) {
        bf16x8 a = *(const bf16x8*)&gzl[cur][n15 * 136 + kt * 32 + quad * 8];
        hb = MFMA(a, ((const bf16x8*)w0L)[(w * 8 + 4 + kt) * 64 + lane], hb);
      }
#pragma unroll
      for (int reg = 0; reg < 4; ++reg)
        hmlp[(quad * 4 + reg) * 136 + w * 16 + n15] = f2bf(tanhfast(hb[reg]));
    }
    if (t > 0) D_STEP(t - 1);
    __syncthreads();  // b1
    // ---- phase 2: C (waves 0-1); hdec chunk flush (waves 4-7, every 4 steps) ----
    if (w < 2) {
      f32x4 mac = {bmv, bmv, bmv, bmv};
#pragma unroll
      for (int kt = 0; kt < 4; ++kt) {
        bf16x8 a = *(const bf16x8*)&hmlp[n15 * 136 + kt * 32 + quad * 8];
        mac = MFMA(a, wmf[kt], mac);
      }
#pragma unroll
      for (int reg = 0; reg < 4; ++reg) {
        int m = quad * 4 + reg;
        if (w == 0) means[m * 17 + n15] = mac[reg];
        else        lvs[m * 17 + n15] = mac[reg];
      }
    } else if (w >= 4 && tt == 0 && t > 0) {
      int t0h = t - 4, tl = tid - 256;
#pragma unroll
      for (int r = 0; r < 4; ++r) {
        int f = r * 256 + tl;                // 1024 uint4
        int ttx = f >> 8, rem = f & 255;
        ((uint4*)(hdec + ((size_t)(t0h + ttx) * BATCH + b0i) * HID))[rem] = ((const uint4*)hdc)[f];
      }
    }
    __syncthreads();  // b2
    // ---- phase 3: Z (reparameterize) ----
    if (tid < 256) {
      int zm = tid >> 4, zo = tid & 15;
      float mean = means[zm * 17 + zo], lv = lvs[zm * 17 + zo];
      float zv = epr * __expf(0.5f * lv) + mean;
      zt[zm * 40 + zo] = f2bf(zv);
      mlzc[0][tt * 256 + tid] = mean;
      mlzc[1][tt * 256 + tid] = lv;
      mlzc[2][tt * 256 + tid] = zv;
    }
    __syncthreads();  // b3
    // ---- phase 4: A(t) g_z cell + gx stage + mlz flush (every 4 steps) ----
    {
      bf16x8 za = *(const bf16x8*)&zt[n15 * 40 + quad * 8];
      bf16x8 gzf[4];
#pragma unroll
      for (int kt = 0; kt < 4; ++kt)
        gzf[kt] = *(const bf16x8*)&gzl[cur][n15 * 136 + kt * 32 + quad * 8];
      float act[4][4];
#pragma unroll
      for (int ct = 0; ct < 4; ++ct) {
        f32x4 ga = {bzr[ct], bzr[ct], bzr[ct], bzr[ct]};
#pragma unroll
        for (int kt = 0; kt < 4; ++kt) ga = MFMA(gzf[kt], whz[ct][kt], ga);
        ga = MFMA(za, whz[ct][4], ga);
#pragma unroll
        for (int reg = 0; reg < 4; ++reg) act[ct][reg] = gate_act(ga[reg], ct == 2);
      }
#pragma unroll
      for (int reg = 0; reg < 4; ++reg) {
        c[reg] = act[1][reg] * c[reg] + act[0][reg] * act[2][reg];
        float h = act[3][reg] * tanhfast(c[reg]);
        gzl[cur ^ 1][(quad * 4 + reg) * 136 + w * 16 + n15] = f2bf(h);
      }
    }
    if (tid < 256) {
      *(uint4*)&gxl[cur ^ 1][(tid >> 4) * 136 + (tid & 15) * 8] = vgx;
      epr = epn;
    }
    if (tt == 3) {     // flush mean/logvar/z for t-3..t (coalesced float2)
      int t0m = t - 3;
      int p = tid >> 1, half = tid & 1;
      int bq = p >> 4, oq = p & 15;
#pragma unroll
      for (int arr = 0; arr < 3; ++arr) {
        float v0 = mlzc[arr][(half * 2) * 256 + p];
        float v1 = mlzc[arr][(half * 2 + 1) * 256 + p];
        float* dst = (arr == 0) ? out_mean : (arr == 1) ? out_logvar : out_z;
        float2 pr; pr.x = v0; pr.y = v1;
        *(float2*)&dst[((size_t)(b0i + bq) * ZD + oq) * T_SEQ + t0m + half * 2] = pr;
      }
    }
    __syncthreads();  // b4
  }
  // epilogue: final decoder step D(511), then flush hdec 508..511
  D_STEP(T_SEQ - 1);
  __syncthreads();
#pragma unroll
  for (int r = 0; r < 2; ++r) {
    int f = r * 512 + tid;                 // 1024 uint4
    int ttx = f >> 8, rem = f & 255;
    ((uint4*)(hdec + ((size_t)(T_SEQ - 4 + ttx) * BATCH + b0i) * HID))[rem] = ((const uint4*)hdc)[f];
  }
}

// ---------- kernel 5: y = exp(hdec @ Wy^T + by) via MFMA, N-dim = t ----------
// block: (b, t-tile 64), 256 thr. A = Wy frags (rows=d), B = hdec tile (cols=t).
__global__ __launch_bounds__(256) void k_y(
    const uint16_t* __restrict__ hdec, const uint4* __restrict__ pk,
    const float* __restrict__ by, float* __restrict__ out_y) {
  __shared__ uint16_t hs[64 * 136];
  int tid = threadIdx.x;
  int t0 = blockIdx.x * 64, b = blockIdx.y;
#pragma unroll
  for (int r = 0; r < 4; ++r) {
    int f = r * 256 + tid;                 // 1024 uint4 (64 rows x 16)
    int tl = f >> 4, q = f & 15;
    uint4 v = ((const uint4*)(hdec + ((size_t)(t0 + tl) * BATCH + b) * HID))[q];
    *(uint4*)&hs[tl * 136 + q * 8] = v;
  }
  __syncthreads();
  int lane = tid & 63, w = tid >> 6;
  int n15 = lane & 15, quad = lane >> 4;
  const bf16x8* pkb = (const bf16x8*)pk;
  for (int nt = 0; nt < 4; ++nt) {
    bf16x8 bf[4];
#pragma unroll
    for (int kt = 0; kt < 4; ++kt)
      bf[kt] = *(const bf16x8*)&hs[(nt * 16 + n15) * 136 + kt * 32 + quad * 8];
    for (int mt = w; mt < 17; mt += 4) {
      f32x4 acc;
#pragma unroll
      for (int reg = 0; reg < 4; ++reg) {
        int d = mt * 16 + quad * 4 + reg;
        acc[reg] = (d < XD) ? by[d] : 0.0f;
      }
#pragma unroll
      for (int kt = 0; kt < 4; ++kt)
        acc = MFMA(pkb[OPY + (mt * 4 + kt) * 64 + lane], bf[kt], acc);
#pragma unroll
      for (int reg = 0; reg < 4; ++reg) {
        int d = mt * 16 + quad * 4 + reg;
        if (d < XD)
          out_y[((size_t)b * XD + d) * T_SEQ + t0 + nt * 16 + n15] = __expf(acc[reg]);
      }
    }
  }
}

extern "C" void kernel_launch(void* const* d_in, const int* in_sizes, int n_in,
                              void* d_out, int out_size, void* d_ws, size_t ws_size,
                              hipStream_t stream) {
  const float* x      = (const float*)d_in[0];
  const float* eps    = (const float*)d_in[1];
  const float* Wih_gx = (const float*)d_in[2];
  const float* Whh_gx = (const float*)d_in[3];
  const float* bih_gx = (const float*)d_in[4];
  const float* bhh_gx = (const float*)d_in[5];
  const float* Wih_gz = (const float*)d_in[6];
  const float* Whh_gz = (const float*)d_in[7];
  const float* bih_gz = (const float*)d_in[8];
  const float* bhh_gz = (const float*)d_in[9];
  const float* W0     = (const float*)d_in[10];
  const float* b0     = (const float*)d_in[11];
  const float* Wm     = (const float*)d_in[12];
  const float* bm     = (const float*)d_in[13];
  const float* Wv     = (const float*)d_in[14];
  const float* bv     = (const float*)d_in[15];
  const float* Wih_h  = (const float*)d_in[16];
  const float* Whh_h  = (const float*)d_in[17];
  const float* bih_h  = (const float*)d_in[18];
  const float* bhh_h  = (const float*)d_in[19];
  const float* Wy     = (const float*)d_in[20];
  const float* by     = (const float*)d_in[21];

  char* ws = (char*)d_ws;
  uint4*    pkw  = (uint4*)(ws + 0);                  // 897,024 B packed frags
  uint16_t* px   = (uint16_t*)(ws + 1048576);         // bf16 T*B*512 = 134,217,728 B
  uint16_t* gx   = (uint16_t*)(ws + 135266304);       // bf16 T*B*128 =  33,554,432 B
  uint16_t* hdec = (uint16_t*)(ws + 168820736);       // bf16 T*B*128 =  33,554,432 B
  // end: 202,375,168 B

  float* out_y      = (float*)d_out;                       // (B,257,T)
  float* out_mean   = out_y + (size_t)BATCH * XD * T_SEQ;  // (B,16,T)
  float* out_logvar = out_mean + (size_t)BATCH * ZD * T_SEQ;
  float* out_z      = out_logvar + (size_t)BATCH * ZD * T_SEQ;

  k_pack<<<dim3(NPACK / 256), dim3(256), 0, stream>>>(
      Whh_gx, Whh_gz, Whh_h, Wih_gz, Wih_h, W0, Wm, Wv, Wih_gx, Wy, pkw);
  k_proj2<<<dim3(128, 16), dim3(256), 0, stream>>>(x, pkw, bih_gx, bhh_gx, px);
  k_lstm_gx<<<dim3(16), dim3(512), 0, stream>>>(px, pkw, gx);
  k_infdec<<<dim3(16), dim3(512), 0, stream>>>(gx, eps, pkw, bih_gz, bhh_gz,
                                               b0, bm, bv, bih_h, bhh_h,
                                               hdec, out_mean, out_logvar, out_z);
  k_y<<<dim3(8, 256), dim3(256), 0, stream>>>(hdec, pkw, by, out_y);
}